// Round 14
// baseline (745.594 us; speedup 1.0000x reference)
//
#include <hip/hip_runtime.h>
#include <hip/hip_fp16.h>
#include <math.h>

// LSTM: B=512, T=512, D=128, H=64. out = h_T [512,64] fp32.
// Phase 1 (xg_gemm2): xg = x@W_ih^T + b via bf16-MFMA (hi/lo x), CELL-MAJOR f16:
//   per (b,t,j) an 8B packet {i,f | g,o}.
// Phase 2 (lstm_rec12): MFMA recurrence, 32 blocks x 4 waves. Block = 16-row
//   tile; wave q owns N-tiles {q,4+q,8+q,12+q} -> lane-local i,f,g,o per cell
//   (fragment layout copied from the session-validated xg_gemm2). f16 MFMA
//   (= fdot2 precision), 8 MFMA/step. Per-wave LDS/step: 2 b128 A-frag reads
//   + 4 b16 h writes (XOR-swizzled buffer, conflict-free) vs r8's 8 b128 —
//   attacks the shared-LDS-pipe + latency chain that pinned r4-r13 at
//   ~1256 cyc/step.

#define Bsz   512
#define Tlen  512
#define Din   128
#define Hdim  64
#define NGATE 256

typedef __attribute__((ext_vector_type(8))) short short8v;
typedef __attribute__((ext_vector_type(8))) _Float16 half8v;
typedef __attribute__((ext_vector_type(4))) float f32x4;
typedef unsigned short ushort_t;
typedef unsigned int uint_t;

__device__ __forceinline__ unsigned short f2bf_bits(float f) {
    union { float f; unsigned u; } v; v.f = f;
    unsigned r = v.u + 0x7fff + ((v.u >> 16) & 1);   // RNE
    return (unsigned short)(r >> 16);
}
__device__ __forceinline__ float bf2f(unsigned short b) {
    union { unsigned u; float f; } v; v.u = ((unsigned)b) << 16;
    return v.f;
}
__device__ __forceinline__ uint_t pkh(float a, float b) {   // pack 2xf16 (RNE)
    return (uint_t)__half_as_ushort(__float2half(a)) |
           ((uint_t)__half_as_ushort(__float2half(b)) << 16);
}
__device__ __forceinline__ float f16lo(uint_t u) {
    return __half2float(__ushort_as_half((ushort_t)(u & 0xffff)));
}
__device__ __forceinline__ float f16hi(uint_t u) {
    return __half2float(__ushort_as_half((ushort_t)(u >> 16)));
}
__device__ __forceinline__ float sigmoid_f(float v) {
    return 1.0f / (1.0f + __expf(-v));
}
__device__ __forceinline__ float tanh_f(float v) {
    float a = fabsf(v);
    float e = __expf(2.0f * a);
    float r = 1.0f - 2.0f / (e + 1.0f);
    return copysignf(r, v);
}

#define MF(acc, a, b) acc = __builtin_amdgcn_mfma_f32_16x16x32_bf16(a, b, acc, 0, 0, 0)
#define MFH(acc, a, b) acc = __builtin_amdgcn_mfma_f32_16x16x32_f16(a, b, acc, 0, 0, 0)

// ---------------- Phase 1: xg cell-major f16 (unchanged, ~roofline) -----------
__global__ __launch_bounds__(256, 1)
void xg_gemm2(const float* __restrict__ x, const float* __restrict__ W_ih,
              const float* __restrict__ b_ih, const float* __restrict__ b_hh,
              uint_t* __restrict__ xg)
{
    __shared__ __align__(16) ushort_t sxh[2][16][136];  // x-tile hi (pad 136)
    __shared__ __align__(16) ushort_t sxl[2][16][136];  // x-tile lo

    const int tid = threadIdx.x;
    const int l = tid & 63, q = tid >> 6;
    const int jl = l & 15, s4 = l >> 4;
    const int rb = blockIdx.x & 31, tc = blockIdx.x >> 5;
    const int t0 = tc * 32;

    short8v wb[4][4];
    #pragma unroll
    for (int tt = 0; tt < 4; ++tt) {
        #pragma unroll
        for (int kt = 0; kt < 4; ++kt) {
            const float* wp = W_ih + (size_t)(tt * 64 + q * 16 + jl) * Din + kt * 32 + s4 * 8;
            f32x4 v0 = *(const f32x4*)wp;
            f32x4 v1 = *(const f32x4*)(wp + 4);
            #pragma unroll
            for (int j = 0; j < 8; ++j)
                wb[tt][kt][j] = (short)f2bf_bits((j < 4) ? v0[j] : v1[j - 4]);
        }
    }
    float bias[4];
    #pragma unroll
    for (int tt = 0; tt < 4; ++tt) {
        int g = tt * 64 + q * 16 + jl;
        bias[tt] = b_ih[g] + b_hh[g];
    }

    const int srow = tid >> 4, spart = tid & 15;
    const float* xrow = x + (size_t)(rb * 16 + srow) * Tlen * Din + spart * 8;
    f32x4 xr0 = *(const f32x4*)(xrow + (size_t)t0 * Din);
    f32x4 xr1 = *(const f32x4*)(xrow + (size_t)t0 * Din + 4);

    for (int ti = 0; ti < 32; ++ti) {
        const int t = t0 + ti, buf = ti & 1;

        short8v vh, vl;
        #pragma unroll
        for (int j = 0; j < 8; ++j) {
            float f = (j < 4) ? xr0[j] : xr1[j - 4];
            unsigned short hb = f2bf_bits(f);
            vh[j] = (short)hb;
            vl[j] = (short)f2bf_bits(f - bf2f(hb));
        }
        *(short8v*)&sxh[buf][srow][spart * 8] = vh;
        *(short8v*)&sxl[buf][srow][spart * 8] = vl;
        __syncthreads();

        if (ti + 1 < 32) {
            xr0 = *(const f32x4*)(xrow + (size_t)(t + 1) * Din);
            xr1 = *(const f32x4*)(xrow + (size_t)(t + 1) * Din + 4);
        }

        f32x4 acc0 = {0.f, 0.f, 0.f, 0.f}, acc1 = acc0, acc2 = acc0, acc3 = acc0;
        #pragma unroll
        for (int kt = 0; kt < 4; ++kt) {
            short8v ah = *(const short8v*)&sxh[buf][jl][kt * 32 + s4 * 8];
            short8v al = *(const short8v*)&sxl[buf][jl][kt * 32 + s4 * 8];
            MF(acc0, ah, wb[0][kt]); MF(acc1, ah, wb[1][kt]);
            MF(acc2, ah, wb[2][kt]); MF(acc3, ah, wb[3][kt]);
            MF(acc0, al, wb[0][kt]); MF(acc1, al, wb[1][kt]);
            MF(acc2, al, wb[2][kt]); MF(acc3, al, wb[3][kt]);
        }

        // C layout: col(gate-sub)=jl, row(batch-sub)=s4*4+r. Cell-major store.
        #pragma unroll
        for (int r = 0; r < 4; ++r) {
            const int brow = rb * 16 + s4 * 4 + r;
            uint2 st;
            st.x = pkh(acc0[r] + bias[0], acc1[r] + bias[1]);   // i, f
            st.y = pkh(acc2[r] + bias[2], acc3[r] + bias[3]);   // g, o
            *(uint2*)(xg + ((size_t)brow * Tlen + t) * 128 + (q * 16 + jl) * 2) = st;
        }
    }
}

// ---------------- Phase 2: MFMA recurrence v2 ---------------------------------
// 32 blocks x 256 thr (4 waves, 1/SIMD). Block = rows [16rb,16rb+16).
// Wave q: N-tiles {q,4+q,8+q,12+q} -> lane-local cell update for cell
// 16q+(l&15), rows 16rb+(l>>4)*4+0..3.
__global__ __launch_bounds__(256, 1)
void lstm_rec12(const uint_t* __restrict__ xg, const float* __restrict__ W_hh,
                float* __restrict__ out)
{
    __shared__ __align__(16) ushort_t hsw[2 * 16 * 64];  // swizzled f16 h, 4KB

    const int tid = threadIdx.x;
    const int l = tid & 63, q = tid >> 6;
    const int cl = l & 15;        // A-row / C-col lane index
    const int s4 = l >> 4;        // 0..3
    const int rb = blockIdx.x;    // row-tile 0..31
    const int cell = 16 * q + cl; // this lane's cell (C col)
    const int row0 = s4 * 4;      // local rows row0..row0+3 (C rows)

    // B fragments Wf[tt][kh]: B[col = gate tt*64+cell][k = kh*32 + s4*8 + j]
    half8v Wf[4][2];
    #pragma unroll
    for (int tt = 0; tt < 4; ++tt) {
        #pragma unroll
        for (int kh = 0; kh < 2; ++kh) {
            const float* wp = W_hh + (size_t)(tt * 64 + cell) * Hdim + kh * 32 + s4 * 8;
            #pragma unroll
            for (int jj = 0; jj < 8; ++jj)
                Wf[tt][kh][jj] = (_Float16)wp[jj];
        }
    }

    // zero h buffer 0 (1024 ushorts = 512 uints)
    {
        uint_t* hz = (uint_t*)hsw;
        hz[tid] = 0u;
        hz[256 + tid] = 0u;
    }

    f32x4 cst = {0.f, 0.f, 0.f, 0.f};
    f32x4 hfv = {0.f, 0.f, 0.f, 0.f};

    // xg packets: row r of this lane -> ((grow*Tlen + t)*64 + cell)*2 uints
    const uint_t* xr0p = xg + (((size_t)(rb * 16 + row0 + 0) * Tlen) * 64 + cell) * 2;
    const uint_t* xr1p = xg + (((size_t)(rb * 16 + row0 + 1) * Tlen) * 64 + cell) * 2;
    const uint_t* xr2p = xg + (((size_t)(rb * 16 + row0 + 2) * Tlen) * 64 + cell) * 2;
    const uint_t* xr3p = xg + (((size_t)(rb * 16 + row0 + 3) * Tlen) * 64 + cell) * 2;

    // prefetch t=0 and t=1 (stride per t = 128 uints)
    uint2 xc0 = *(const uint2*)xr0p, xc1 = *(const uint2*)xr1p;
    uint2 xc2 = *(const uint2*)xr2p, xc3 = *(const uint2*)xr3p;
    uint2 xn0 = *(const uint2*)(xr0p + 128), xn1 = *(const uint2*)(xr1p + 128);
    uint2 xn2 = *(const uint2*)(xr2p + 128), xn3 = *(const uint2*)(xr3p + 128);

    // A-frag read offsets (ushort idx): row=cl, chunk = kh*4+s4, swz ^= (cl&7)
    const int ra0 = cl * 64 + ((0 * 4 + s4) ^ (cl & 7)) * 8;
    const int ra1 = cl * 64 + ((1 * 4 + s4) ^ (cl & 7)) * 8;
    // h-write offsets per reg r: row = row0+r, chunk = cell>>3, swz ^= (row&7)
    const int wchunk = cell >> 3, wlow = cell & 7;

    __syncthreads();

    for (int t = 0; t < Tlen; ++t) {
        const int buf = t & 1;

        // A fragments: 2 x ds_read_b128 (swizzled, conflict-free)
        half8v a0 = *(const half8v*)&hsw[buf * 1024 + ra0];
        half8v a1 = *(const half8v*)&hsw[buf * 1024 + ra1];

        // prefetch xg(t+2), clamped tail
        const int tn = (t + 2 < Tlen) ? t + 2 : Tlen - 1;
        uint2 xp0 = *(const uint2*)(xr0p + (size_t)tn * 128);
        uint2 xp1 = *(const uint2*)(xr1p + (size_t)tn * 128);
        uint2 xp2 = *(const uint2*)(xr2p + (size_t)tn * 128);
        uint2 xp3 = *(const uint2*)(xr3p + (size_t)tn * 128);

        // C init from xg packets: acc_tt[r] = gate tt of (row0+r, cell) at t
        f32x4 acc0 = {f16lo(xc0.x), f16lo(xc1.x), f16lo(xc2.x), f16lo(xc3.x)}; // i
        f32x4 acc1 = {f16hi(xc0.x), f16hi(xc1.x), f16hi(xc2.x), f16hi(xc3.x)}; // f
        f32x4 acc2 = {f16lo(xc0.y), f16lo(xc1.y), f16lo(xc2.y), f16lo(xc3.y)}; // g
        f32x4 acc3 = {f16hi(xc0.y), f16hi(xc1.y), f16hi(xc2.y), f16hi(xc3.y)}; // o

        // 8 MFMA: gates += h(16x64) @ W^T tiles
        MFH(acc0, a0, Wf[0][0]); MFH(acc1, a0, Wf[1][0]);
        MFH(acc2, a0, Wf[2][0]); MFH(acc3, a0, Wf[3][0]);
        MFH(acc0, a1, Wf[0][1]); MFH(acc1, a1, Wf[1][1]);
        MFH(acc2, a1, Wf[2][1]); MFH(acc3, a1, Wf[3][1]);

        // lane-local cell update for 4 rows
        #pragma unroll
        for (int r = 0; r < 4; ++r) {
            float iv = sigmoid_f(acc0[r]);
            float fv = sigmoid_f(acc1[r]);
            float gv = tanh_f(acc2[r]);
            float ov = sigmoid_f(acc3[r]);
            float cc = fv * cst[r] + iv * gv;
            cst[r] = cc;
            float hh = ov * tanh_f(cc);
            hfv[r] = hh;
            const int row = row0 + r;
            hsw[(buf ^ 1) * 1024 + row * 64 + (wchunk ^ (row & 7)) * 8 + wlow] =
                __half_as_ushort(__float2half(hh));
        }
        __syncthreads();

        xc0 = xn0; xc1 = xn1; xc2 = xn2; xc3 = xn3;
        xn0 = xp0; xn1 = xp1; xn2 = xp2; xn3 = xp3;
    }

    #pragma unroll
    for (int r = 0; r < 4; ++r)
        out[(size_t)(rb * 16 + row0 + r) * Hdim + cell] = hfv[r];
}

// ---------------- Fallback: round-1 fused kernel (proven correct) -------------
#define LDS_DWORDS 33920
__global__ void __launch_bounds__(256, 1)
lstm_fused(const float* __restrict__ x, const float* __restrict__ W_ih,
           const float* __restrict__ W_hh, const float* __restrict__ b_ih,
           const float* __restrict__ b_hh, float* __restrict__ out)
{
    extern __shared__ float lds[];
    float* wih   = lds;
    float* xbuf  = lds + 32768;
    float* gates = lds + 33280;
    float* hbuf  = lds + 33792;

    const int tid = threadIdx.x;
    const int g   = tid;
    const int row_base = blockIdx.x * 2;

    {
        const float4* src = reinterpret_cast<const float4*>(W_ih);
        float4* dst = reinterpret_cast<float4*>(wih);
        #pragma unroll
        for (int i = 0; i < 32; ++i) {
            int qq = i * 256 + tid;
            int rg = qq >> 5;
            int cc = qq & 31;
            dst[rg * 32 + (cc ^ (rg & 7))] = src[qq];
        }
    }
    float4 whh[16];
    {
        const float4* src = reinterpret_cast<const float4*>(W_hh) + g * 16;
        #pragma unroll
        for (int cc = 0; cc < 16; ++cc) whh[cc] = src[cc];
    }
    const float bias = b_ih[g] + b_hh[g];
    if (tid < 128) hbuf[tid] = 0.0f;
    {
        int r = tid >> 7, k = tid & 127;
        xbuf[tid] = x[((size_t)(row_base + r) * Tlen + 0) * Din + k];
    }
    float cstate = 0.0f, hval = 0.0f;
    __syncthreads();

    int cur = 0;
    const int sw = g & 7;
    const float4* w4 = reinterpret_cast<const float4*>(wih) + g * 32;

    for (int t = 0; t < Tlen; ++t) {
        float xnext = 0.0f;
        if (t + 1 < Tlen) {
            int r = tid >> 7, k = tid & 127;
            xnext = x[((size_t)(row_base + r) * Tlen + (t + 1)) * Din + k];
        }
        float acc0 = bias, acc1 = bias;
        {
            const float4* xr0 = reinterpret_cast<const float4*>(xbuf + cur * 256);
            const float4* xr1 = reinterpret_cast<const float4*>(xbuf + cur * 256 + 128);
            #pragma unroll 8
            for (int cc = 0; cc < 32; ++cc) {
                float4 w = w4[cc ^ sw];
                float4 a = xr0[cc];
                float4 bb = xr1[cc];
                acc0 += w.x * a.x + w.y * a.y + w.z * a.z + w.w * a.w;
                acc1 += w.x * bb.x + w.y * bb.y + w.z * bb.z + w.w * bb.w;
            }
        }
        {
            const float4* h0 = reinterpret_cast<const float4*>(hbuf);
            const float4* h1 = reinterpret_cast<const float4*>(hbuf + 64);
            #pragma unroll
            for (int cc = 0; cc < 16; ++cc) {
                float4 w = whh[cc];
                float4 a = h0[cc];
                float4 bb = h1[cc];
                acc0 += w.x * a.x + w.y * a.y + w.z * a.z + w.w * a.w;
                acc1 += w.x * bb.x + w.y * bb.y + w.z * bb.z + w.w * bb.w;
            }
        }
        gates[g]       = acc0;
        gates[256 + g] = acc1;
        __syncthreads();

        if (tid < 128) {
            int r = tid >> 6, jj = tid & 63;
            const float* gr = gates + r * 256;
            float ig = sigmoid_f(gr[jj]);
            float fg = sigmoid_f(gr[64 + jj]);
            float gg = tanh_f(gr[128 + jj]);
            float og = sigmoid_f(gr[192 + jj]);
            cstate = fg * cstate + ig * gg;
            hval   = og * tanh_f(cstate);
            hbuf[r * 64 + jj] = hval;
        }
        if (t + 1 < Tlen) xbuf[(cur ^ 1) * 256 + tid] = xnext;
        __syncthreads();
        cur ^= 1;
    }
    if (tid < 128) {
        int r = tid >> 6, jj = tid & 63;
        out[(size_t)(row_base + r) * Hdim + jj] = hval;
    }
}

extern "C" void kernel_launch(void* const* d_in, const int* in_sizes, int n_in,
                              void* d_out, int out_size, void* d_ws, size_t ws_size,
                              hipStream_t stream) {
    const float* x    = (const float*)d_in[0];
    const float* W_ih = (const float*)d_in[1];
    const float* W_hh = (const float*)d_in[2];
    const float* b_ih = (const float*)d_in[3];
    const float* b_hh = (const float*)d_in[4];
    float* out = (float*)d_out;

    const size_t need = (size_t)Bsz * Tlen * NGATE * 2;   // 134,217,728 B (f16 xg)
    if (ws_size >= need) {
        uint_t* xgws = (uint_t*)d_ws;
        xg_gemm2<<<512, 256, 0, stream>>>(x, W_ih, b_ih, b_hh, xgws);
        lstm_rec12<<<Bsz / 16, 256, 0, stream>>>(xgws, W_hh, out);
    } else {
        const size_t lds_bytes = (size_t)LDS_DWORDS * 4;
        hipFuncSetAttribute(reinterpret_cast<const void*>(lstm_fused),
                            hipFuncAttributeMaxDynamicSharedMemorySize, (int)lds_bytes);
        lstm_fused<<<Bsz / 2, 256, lds_bytes, stream>>>(x, W_ih, W_hh, b_ih, b_hh, out);
    }
}

// Round 15
// 285.140 us; speedup vs baseline: 2.6148x; 2.6148x over previous
//
#include <hip/hip_runtime.h>
#include <hip/hip_fp16.h>
#include <math.h>

// LSTM: B=512, T=512, D=128, H=64. out = h_T [512,64] fp32.
// Phase 1 (xg_gemm2): xg = x@W_ih^T + b via bf16-MFMA (hi/lo x), CELL-MAJOR f16:
//   per (b,t,j) an 8B packet {i,f | g,o}.
// Phase 2 (lstm_rec13): 512 blocks x 256 thr (4 waves/row). Wave = 16 cells;
//   lane = cell*4 + gate. Chain surgery vs r8 (both LDS RTs -> one):
//   gate exchange via DPP quad_perm on ACTIVATED values (VALU, no LDS, no
//   redundant trans — fixes r11), activation via tanh(x)=2*sig(2x)-1 (single
//   exp+rcp chain for all gate types). Remaining chain: h-bcast LDS read,
//   one barrier (dbuf h), tanh(c), b16 h-write. xg in 8-step register batches.

#define Bsz   512
#define Tlen  512
#define Din   128
#define Hdim  64
#define NGATE 256

typedef __attribute__((ext_vector_type(8))) short short8v;
typedef __attribute__((ext_vector_type(4))) float f32x4;
typedef __attribute__((ext_vector_type(2))) _Float16 h2v;
typedef unsigned short ushort_t;
typedef unsigned int uint_t;
typedef __attribute__((ext_vector_type(4))) uint_t uint4v;

__device__ __forceinline__ unsigned short f2bf_bits(float f) {
    union { float f; unsigned u; } v; v.f = f;
    unsigned r = v.u + 0x7fff + ((v.u >> 16) & 1);   // RNE
    return (unsigned short)(r >> 16);
}
__device__ __forceinline__ float bf2f(unsigned short b) {
    union { unsigned u; float f; } v; v.u = ((unsigned)b) << 16;
    return v.f;
}
__device__ __forceinline__ uint_t pkh(float a, float b) {   // pack 2xf16 (RNE)
    return (uint_t)__half_as_ushort(__float2half(a)) |
           ((uint_t)__half_as_ushort(__float2half(b)) << 16);
}
__device__ __forceinline__ h2v as_h2(uint_t u) {
    union { uint_t u; h2v h; } v; v.u = u; return v.h;
}
__device__ __forceinline__ float f16lo(uint_t u) {
    return __half2float(__ushort_as_half((ushort_t)(u & 0xffff)));
}
__device__ __forceinline__ float f16hi(uint_t u) {
    return __half2float(__ushort_as_half((ushort_t)(u >> 16)));
}
__device__ __forceinline__ float sigmoid_f(float v) {
    return 1.0f / (1.0f + __expf(-v));
}
__device__ __forceinline__ float tanh_f(float v) {
    float a = fabsf(v);
    float e = __expf(2.0f * a);
    float r = 1.0f - 2.0f / (e + 1.0f);
    return copysignf(r, v);
}

// quad broadcast via DPP quad_perm: every lane gets quad-lane K's value. VALU.
template <int K>
__device__ __forceinline__ float qbcast(float v) {
    constexpr int ctrl = K | (K << 2) | (K << 4) | (K << 6);   // quad_perm [K,K,K,K]
    int r = __builtin_amdgcn_update_dpp(0, __float_as_int(v), ctrl, 0xF, 0xF, true);
    return __int_as_float(r);
}

#if defined(__has_builtin)
#if __has_builtin(__builtin_amdgcn_fdot2)
#define FDOT2(a, b, c) __builtin_amdgcn_fdot2((a), (b), (c), false)
#endif
#endif
#ifndef FDOT2
#define FDOT2(a, b, c) fmaf((float)(a)[1], (float)(b)[1], fmaf((float)(a)[0], (float)(b)[0], (c)))
#endif

#define MF(acc, a, b) acc = __builtin_amdgcn_mfma_f32_16x16x32_bf16(a, b, acc, 0, 0, 0)

// ---------------- Phase 1: xg cell-major f16 (unchanged, ~roofline) -----------
__global__ __launch_bounds__(256, 1)
void xg_gemm2(const float* __restrict__ x, const float* __restrict__ W_ih,
              const float* __restrict__ b_ih, const float* __restrict__ b_hh,
              uint_t* __restrict__ xg)
{
    __shared__ __align__(16) ushort_t sxh[2][16][136];  // x-tile hi (pad 136)
    __shared__ __align__(16) ushort_t sxl[2][16][136];  // x-tile lo

    const int tid = threadIdx.x;
    const int l = tid & 63, q = tid >> 6;
    const int jl = l & 15, s4 = l >> 4;
    const int rb = blockIdx.x & 31, tc = blockIdx.x >> 5;
    const int t0 = tc * 32;

    short8v wb[4][4];
    #pragma unroll
    for (int tt = 0; tt < 4; ++tt) {
        #pragma unroll
        for (int kt = 0; kt < 4; ++kt) {
            const float* wp = W_ih + (size_t)(tt * 64 + q * 16 + jl) * Din + kt * 32 + s4 * 8;
            f32x4 v0 = *(const f32x4*)wp;
            f32x4 v1 = *(const f32x4*)(wp + 4);
            #pragma unroll
            for (int j = 0; j < 8; ++j)
                wb[tt][kt][j] = (short)f2bf_bits((j < 4) ? v0[j] : v1[j - 4]);
        }
    }
    float bias[4];
    #pragma unroll
    for (int tt = 0; tt < 4; ++tt) {
        int g = tt * 64 + q * 16 + jl;
        bias[tt] = b_ih[g] + b_hh[g];
    }

    const int srow = tid >> 4, spart = tid & 15;
    const float* xrow = x + (size_t)(rb * 16 + srow) * Tlen * Din + spart * 8;
    f32x4 xr0 = *(const f32x4*)(xrow + (size_t)t0 * Din);
    f32x4 xr1 = *(const f32x4*)(xrow + (size_t)t0 * Din + 4);

    for (int ti = 0; ti < 32; ++ti) {
        const int t = t0 + ti, buf = ti & 1;

        short8v vh, vl;
        #pragma unroll
        for (int j = 0; j < 8; ++j) {
            float f = (j < 4) ? xr0[j] : xr1[j - 4];
            unsigned short hb = f2bf_bits(f);
            vh[j] = (short)hb;
            vl[j] = (short)f2bf_bits(f - bf2f(hb));
        }
        *(short8v*)&sxh[buf][srow][spart * 8] = vh;
        *(short8v*)&sxl[buf][srow][spart * 8] = vl;
        __syncthreads();

        if (ti + 1 < 32) {
            xr0 = *(const f32x4*)(xrow + (size_t)(t + 1) * Din);
            xr1 = *(const f32x4*)(xrow + (size_t)(t + 1) * Din + 4);
        }

        f32x4 acc0 = {0.f, 0.f, 0.f, 0.f}, acc1 = acc0, acc2 = acc0, acc3 = acc0;
        #pragma unroll
        for (int kt = 0; kt < 4; ++kt) {
            short8v ah = *(const short8v*)&sxh[buf][jl][kt * 32 + s4 * 8];
            short8v al = *(const short8v*)&sxl[buf][jl][kt * 32 + s4 * 8];
            MF(acc0, ah, wb[0][kt]); MF(acc1, ah, wb[1][kt]);
            MF(acc2, ah, wb[2][kt]); MF(acc3, ah, wb[3][kt]);
            MF(acc0, al, wb[0][kt]); MF(acc1, al, wb[1][kt]);
            MF(acc2, al, wb[2][kt]); MF(acc3, al, wb[3][kt]);
        }

        // C layout: col(gate-sub)=jl, row(batch-sub)=s4*4+r. Cell-major store.
        #pragma unroll
        for (int r = 0; r < 4; ++r) {
            const int brow = rb * 16 + s4 * 4 + r;
            uint2 st;
            st.x = pkh(acc0[r] + bias[0], acc1[r] + bias[1]);   // i, f
            st.y = pkh(acc2[r] + bias[2], acc3[r] + bias[3]);   // g, o
            *(uint2*)(xg + ((size_t)brow * Tlen + t) * 128 + (q * 16 + jl) * 2) = st;
        }
    }
}

// ---------------- Phase 2: quad-DPP post-activation exchange ------------------
// 512 blocks x 256 thr (4 waves). Wave w: cells [16w,16w+16); lane = s*4+tt.
__global__ __launch_bounds__(256, 1)
void lstm_rec13(const uint_t* __restrict__ xg, const float* __restrict__ W_hh,
                float* __restrict__ out)
{
    __shared__ __align__(16) ushort_t hsh[2][Hdim];  // f16 h, double-buffered

    const int tid = threadIdx.x;
    const int l  = tid & 63;         // lane
    const int w  = tid >> 6;         // wave 0..3
    const int s  = l >> 2;           // cell slot within wave (quad index)
    const int tt = l & 3;            // gate type: 0=i 1=f 2=g 3=o
    const int j  = w * 16 + s;       // cell 0..63
    const int b  = blockIdx.x;       // batch row

    // W_hh row (tt*64 + j): 32 packed f16x2 in 8 uint4v (32 VGPRs, resident).
    uint4v Wq[8];
    {
        const float2* wr = (const float2*)(W_hh + (size_t)(tt * Hdim + j) * Hdim);
        #pragma unroll
        for (int qq = 0; qq < 8; ++qq) {
            #pragma unroll
            for (int cc = 0; cc < 4; ++cc) {
                float2 ww = wr[qq * 4 + cc];
                Wq[qq][cc] = pkh(ww.x, ww.y);
            }
        }
    }

    if (tid < Hdim) hsh[0][tid] = 0;   // h0 = 0
    float c = 0.0f, h = 0.0f;
    __syncthreads();

    // cell-major xg: dword (tt>>1) of cell j's uint2 packet; stride/t = 128
    const uint_t* xp = xg + (size_t)b * (Tlen * 128) + j * 2 + (tt >> 1);

    // 8-step register batches, A/B double buffer
    uint_t xA[8], xB[8];
    #pragma unroll
    for (int i = 0; i < 8; ++i) xA[i] = xp[(size_t)i * 128];
    #pragma unroll
    for (int i = 0; i < 8; ++i) xB[i] = xp[(size_t)(8 + i) * 128];

#define STEP1(xv, SI) do {                                                     \
    const int buf_ = (SI) & 1;                                                 \
    const uint4v* hp_ = (const uint4v*)&hsh[buf_][0];                          \
    uint4v hq_[8];                                                             \
    _Pragma("unroll")                                                          \
    for (int i_ = 0; i_ < 8; ++i_) hq_[i_] = hp_[i_];                          \
    float a0 = (tt & 1) ? f16hi(xv) : f16lo(xv);                               \
    float a1 = 0.f, a2 = 0.f, a3 = 0.f;                                        \
    _Pragma("unroll")                                                          \
    for (int q_ = 0; q_ < 8; ++q_) {                                           \
        a0 = FDOT2(as_h2(hq_[q_][0]), as_h2(Wq[q_][0]), a0);                   \
        a1 = FDOT2(as_h2(hq_[q_][1]), as_h2(Wq[q_][1]), a1);                   \
        a2 = FDOT2(as_h2(hq_[q_][2]), as_h2(Wq[q_][2]), a2);                   \
        a3 = FDOT2(as_h2(hq_[q_][3]), as_h2(Wq[q_][3]), a3);                   \
    }                                                                          \
    float pre = (a0 + a1) + (a2 + a3);                                         \
    /* single trans chain: tanh(x) = 2*sigmoid(2x)-1 (select on in/out) */     \
    float px  = (tt == 2) ? 2.0f * pre : pre;                                  \
    float sg_ = 1.0f / (1.0f + __expf(-px));                                   \
    float act = (tt == 2) ? 2.0f * sg_ - 1.0f : sg_;                           \
    /* quad exchange of ACTIVATED gates via DPP (VALU, no LDS/barrier) */      \
    float iv = qbcast<0>(act);                                                 \
    float fv = qbcast<1>(act);                                                 \
    float gv = qbcast<2>(act);                                                 \
    float ov = qbcast<3>(act);                                                 \
    c = fv * c + iv * gv;                                                      \
    h = ov * tanh_f(c);                                                        \
    if (tt == 0) hsh[buf_ ^ 1][j] = __half_as_ushort(__float2half(h));         \
    __syncthreads();                                                           \
} while (0)

#define STEP8(XARR) do {                                                       \
    _Pragma("unroll")                                                          \
    for (int si_ = 0; si_ < 8; ++si_) STEP1(XARR[si_], si_);                   \
} while (0)

    for (int bt = 0; bt < 64; bt += 2) {
        STEP8(xA);
        if (bt + 2 < 64) {
            const uint_t* rp = xp + (size_t)(bt + 2) * 8 * 128;
            #pragma unroll
            for (int i = 0; i < 8; ++i) xA[i] = rp[(size_t)i * 128];
        }
        STEP8(xB);
        if (bt + 3 < 64) {
            const uint_t* rp = xp + (size_t)(bt + 3) * 8 * 128;
            #pragma unroll
            for (int i = 0; i < 8; ++i) xB[i] = rp[(size_t)i * 128];
        }
    }
#undef STEP8
#undef STEP1

    if (tt == 0) out[(size_t)b * Hdim + j] = h;
}

// ---------------- Fallback: round-1 fused kernel (proven correct) -------------
#define LDS_DWORDS 33920
__global__ void __launch_bounds__(256, 1)
lstm_fused(const float* __restrict__ x, const float* __restrict__ W_ih,
           const float* __restrict__ W_hh, const float* __restrict__ b_ih,
           const float* __restrict__ b_hh, float* __restrict__ out)
{
    extern __shared__ float lds[];
    float* wih   = lds;
    float* xbuf  = lds + 32768;
    float* gates = lds + 33280;
    float* hbuf  = lds + 33792;

    const int tid = threadIdx.x;
    const int g   = tid;
    const int row_base = blockIdx.x * 2;

    {
        const float4* src = reinterpret_cast<const float4*>(W_ih);
        float4* dst = reinterpret_cast<float4*>(wih);
        #pragma unroll
        for (int i = 0; i < 32; ++i) {
            int qq = i * 256 + tid;
            int rg = qq >> 5;
            int cc = qq & 31;
            dst[rg * 32 + (cc ^ (rg & 7))] = src[qq];
        }
    }
    float4 whh[16];
    {
        const float4* src = reinterpret_cast<const float4*>(W_hh) + g * 16;
        #pragma unroll
        for (int cc = 0; cc < 16; ++cc) whh[cc] = src[cc];
    }
    const float bias = b_ih[g] + b_hh[g];
    if (tid < 128) hbuf[tid] = 0.0f;
    {
        int r = tid >> 7, k = tid & 127;
        xbuf[tid] = x[((size_t)(row_base + r) * Tlen + 0) * Din + k];
    }
    float cstate = 0.0f, hval = 0.0f;
    __syncthreads();

    int cur = 0;
    const int sw = g & 7;
    const float4* w4 = reinterpret_cast<const float4*>(wih) + g * 32;

    for (int t = 0; t < Tlen; ++t) {
        float xnext = 0.0f;
        if (t + 1 < Tlen) {
            int r = tid >> 7, k = tid & 127;
            xnext = x[((size_t)(row_base + r) * Tlen + (t + 1)) * Din + k];
        }
        float acc0 = bias, acc1 = bias;
        {
            const float4* xr0 = reinterpret_cast<const float4*>(xbuf + cur * 256);
            const float4* xr1 = reinterpret_cast<const float4*>(xbuf + cur * 256 + 128);
            #pragma unroll 8
            for (int cc = 0; cc < 32; ++cc) {
                float4 w = w4[cc ^ sw];
                float4 a = xr0[cc];
                float4 bb = xr1[cc];
                acc0 += w.x * a.x + w.y * a.y + w.z * a.z + w.w * a.w;
                acc1 += w.x * bb.x + w.y * bb.y + w.z * bb.z + w.w * bb.w;
            }
        }
        {
            const float4* h0 = reinterpret_cast<const float4*>(hbuf);
            const float4* h1 = reinterpret_cast<const float4*>(hbuf + 64);
            #pragma unroll
            for (int cc = 0; cc < 16; ++cc) {
                float4 w = whh[cc];
                float4 a = h0[cc];
                float4 bb = h1[cc];
                acc0 += w.x * a.x + w.y * a.y + w.z * a.z + w.w * a.w;
                acc1 += w.x * bb.x + w.y * bb.y + w.z * bb.z + w.w * bb.w;
            }
        }
        gates[g]       = acc0;
        gates[256 + g] = acc1;
        __syncthreads();

        if (tid < 128) {
            int r = tid >> 6, jj = tid & 63;
            const float* gr = gates + r * 256;
            float ig = sigmoid_f(gr[jj]);
            float fg = sigmoid_f(gr[64 + jj]);
            float gg = tanh_f(gr[128 + jj]);
            float og = sigmoid_f(gr[192 + jj]);
            cstate = fg * cstate + ig * gg;
            hval   = og * tanh_f(cstate);
            hbuf[r * 64 + jj] = hval;
        }
        if (t + 1 < Tlen) xbuf[(cur ^ 1) * 256 + tid] = xnext;
        __syncthreads();
        cur ^= 1;
    }
    if (tid < 128) {
        int r = tid >> 6, jj = tid & 63;
        out[(size_t)(row_base + r) * Hdim + jj] = hval;
    }
}

extern "C" void kernel_launch(void* const* d_in, const int* in_sizes, int n_in,
                              void* d_out, int out_size, void* d_ws, size_t ws_size,
                              hipStream_t stream) {
    const float* x    = (const float*)d_in[0];
    const float* W_ih = (const float*)d_in[1];
    const float* W_hh = (const float*)d_in[2];
    const float* b_ih = (const float*)d_in[3];
    const float* b_hh = (const float*)d_in[4];
    float* out = (float*)d_out;

    const size_t need = (size_t)Bsz * Tlen * NGATE * 2;   // 134,217,728 B (f16 xg)
    if (ws_size >= need) {
        uint_t* xgws = (uint_t*)d_ws;
        xg_gemm2<<<512, 256, 0, stream>>>(x, W_ih, b_ih, b_hh, xgws);
        lstm_rec13<<<Bsz, 256, 0, stream>>>(xgws, W_hh, out);
    } else {
        const size_t lds_bytes = (size_t)LDS_DWORDS * 4;
        hipFuncSetAttribute(reinterpret_cast<const void*>(lstm_fused),
                            hipFuncAttributeMaxDynamicSharedMemorySize, (int)lds_bytes);
        lstm_fused<<<Bsz / 2, 256, lds_bytes, stream>>>(x, W_ih, W_hh, b_ih, b_hh, out);
    }
}